// Round 8
// baseline (501.469 us; speedup 1.0000x reference)
//
#include <hip/hip_runtime.h>
#include <cstdint>
#include <math.h>

typedef _Float16 f16;
typedef f16 f16x8 __attribute__((ext_vector_type(8)));
typedef f16 f16x4 __attribute__((ext_vector_type(4)));
typedef float f32x4 __attribute__((ext_vector_type(4)));

#define BATCH 2
#define TSEQ 4096
#define WID 2048
#define LRU 2048
#define NHEAD 8
#define HDIM 256
#define MTOT (BATCH * TSEQ)   // 8192
#define CT 128                // scan chunk length == gates m-tile
#define NC (TSEQ / CT)        // 32 chunks

// ---------- async global -> LDS, 16B per lane ----------
__device__ __forceinline__ void gl2lds16(const f16* g, f16* l) {
  __builtin_amdgcn_global_load_lds(
      (__attribute__((address_space(1))) uint32_t*)(uintptr_t)g,
      (__attribute__((address_space(3))) uint32_t*)(uint32_t)(uintptr_t)l,
      16, 0, 0);
}

__device__ __forceinline__ float fast_rcp(float x) {
  float r; asm("v_rcp_f32 %0, %1" : "=v"(r) : "v"(x)); return r;
}
// fast sigmoid: v_exp-based exp (2 inst) + v_rcp (1 inst). ~1 ulp vs libm;
// downstream values are f16/16-bit-fixed quantized, so this is below the
// existing quantization noise floor.
__device__ __forceinline__ float fast_sigmoid(float x) {
  return fast_rcp(1.f + __expf(-x));
}
__device__ __forceinline__ float f16bits_to_f(uint32_t b) {
  return (float)__builtin_bit_cast(f16, (uint16_t)b);
}

// ---------- prep megakernel: cast x -> f16, transpose+cast all weights, softplus table ----------
// blocks [0,16384): cast; [16384,28672): 3x 2048^2 transpose; [28672,29696): 16x 256^2;
// [29696,29704): spT = softplus(a_param) (precise libm, computed once)
__global__ void prep_kernel(const float* __restrict__ x, f16* __restrict__ Xh,
                            const float* __restrict__ w_y, const float* __restrict__ w_x,
                            const float* __restrict__ w_out,
                            f16* __restrict__ wyT, f16* __restrict__ wxT, f16* __restrict__ woutT,
                            const float* __restrict__ ig, const float* __restrict__ ag,
                            f16* __restrict__ igT, f16* __restrict__ agT,
                            const float* __restrict__ ap, float* __restrict__ spT) {
  __shared__ float tile[32][33];
  const int bid = blockIdx.x, t = threadIdx.x;
  if (bid < 16384) {
    int i = bid * 256 + t;
    float4 v = ((const float4*)x)[i];
    f16x4 o = { (f16)v.x, (f16)v.y, (f16)v.z, (f16)v.w };
    ((f16x4*)Xh)[i] = o;
    return;
  }
  if (bid >= 29696) {
    int i = (bid - 29696) * 256 + t;
    spT[i] = log1pf(expf(ap[i]));
    return;
  }
  const int tx = t & 31, ty = t >> 5;
  const float* ib; f16* ob; int R, C, c0, r0;
  if (bid < 28672) {
    int idx = bid - 16384;
    int z = idx >> 12, tl = idx & 4095;
    ib = z == 0 ? w_y : (z == 1 ? w_x : w_out);
    ob = z == 0 ? wyT : (z == 1 ? wxT : woutT);
    R = 2048; C = 2048;
    c0 = (tl & 63) * 32; r0 = (tl >> 6) * 32;
  } else {
    int idx = bid - 28672;
    int z = idx >> 6, tl = idx & 63;
    ib = (z < 8 ? ig : ag) + (long long)(z & 7) * HDIM * HDIM;
    ob = (z < 8 ? igT : agT) + (long long)(z & 7) * HDIM * HDIM;
    R = HDIM; C = HDIM;
    c0 = (tl & 7) * 32; r0 = (tl >> 3) * 32;
  }
#pragma unroll
  for (int i = 0; i < 32; i += 8)
    tile[ty + i][tx] = ib[(long long)(r0 + ty + i) * C + c0 + tx];
  __syncthreads();
#pragma unroll
  for (int i = 0; i < 32; i += 8)
    ob[(long long)(c0 + ty + i) * R + r0 + tx] = (f16)tile[tx][ty + i];
}

// ---------- 128x128 m97-style GEMM, BK=64, 3 blocks/CU ----------
// C[M,N] = A[M,K] @ BT[N,K]^T + bias.  MODE 0: f16 out, tanh-GELU; 1: f16 out; 2: f32 out.
// Occupancy does the latency hiding (m97 mechanism): single-buffered 32 KB LDS,
// plain __syncthreads (full drain), 3 blocks x 4 waves = 12 waves/CU; the cross-block
// wave overlap fills the matrix pipe during this block's stage/drain/read regions.
// (Measured: 1-block/CU 256^2 deep-pipelined variants all serialize at ~755 TF here.)
// 16B-granule XOR swizzle (involution g ^= row&7) applied to BOTH the global source
// column and the LDS read slot; LDS dest stays linear (global_load_lds-safe; 0-conflict
// verified by SQ_LDS_BANK_CONFLICT=0 with the same pattern).
template <int MODE>
__global__ __launch_bounds__(256, 3) void gemm_128(
    const f16* __restrict__ A, const f16* __restrict__ BT,
    const float* __restrict__ bias, void* __restrict__ Cout,
    int M, int N, int K) {
  __shared__ __align__(16) f16 As[128 * 64];   // 16 KB
  __shared__ __align__(16) f16 Bs[128 * 64];   // 16 KB
  const int m0 = blockIdx.x * 128, n0 = blockIdx.y * 128;
  const int t = threadIdx.x;
  const int lane = t & 63, wave = t >> 6;
  const int wr = (wave >> 1) * 64, wc = (wave & 1) * 64;
  const int l15 = lane & 15, quad = lane >> 4;
  const int srow = t >> 3;                       // 0..31 (8 threads x 16B per 128B row)
  const int sg = ((t & 7) ^ (srow & 7)) * 8;     // swizzled source granule col (f16 units)

  const f16* Ag = A + (long long)(m0 + srow) * K + sg;
  const f16* Bg = BT + (long long)(n0 + srow) * K + sg;
  const long long r32 = (long long)32 * K;       // +32 rows: row&7 invariant

  f32x4 c[4][4] = {};
  const int NT = K >> 6;
  for (int kt = 0; kt < NT; ++kt) {
    const f16* a = Ag + kt * 64;
    const f16* b = Bg + kt * 64;
#pragma unroll
    for (int cc = 0; cc < 4; ++cc) {
      gl2lds16(a + cc * r32, &As[cc * 2048 + t * 8]);
      gl2lds16(b + cc * r32, &Bs[cc * 2048 + t * 8]);
    }
    __syncthreads();   // drains vmcnt: tiles landed + visible
    f16x8 af[4][2], bf[4][2];
#pragma unroll
    for (int f = 0; f < 4; ++f) {
#pragma unroll
      for (int kh = 0; kh < 2; ++kh) {
        const int sa = ((kh * 4 + quad) ^ (l15 & 7)) * 8;   // swizzled read slot
        af[f][kh] = *(const f16x8*)&As[(wr + f * 16 + l15) * 64 + sa];
        bf[f][kh] = *(const f16x8*)&Bs[(wc + f * 16 + l15) * 64 + sa];
      }
    }
#pragma unroll
    for (int kh = 0; kh < 2; ++kh)
#pragma unroll
      for (int i = 0; i < 4; ++i)
#pragma unroll
        for (int j = 0; j < 4; ++j)
          c[i][j] = __builtin_amdgcn_mfma_f32_16x16x32_f16(af[i][kh], bf[j][kh], c[i][j], 0, 0, 0);
    __syncthreads();   // all reads done before next stage overwrites (WAR)
  }
#pragma unroll
  for (int i = 0; i < 4; ++i) {
#pragma unroll
    for (int j = 0; j < 4; ++j) {
      const int col = n0 + wc + j * 16 + l15;
      const float bv = bias[col];
      const int row0 = m0 + wr + i * 16 + quad * 4;
#pragma unroll
      for (int r = 0; r < 4; ++r) {
        float v = c[i][j][r] + bv;
        long long off = (long long)(row0 + r) * N + col;
        if constexpr (MODE == 0) {
          float u = v + 0.044715f * v * v * v;
          float g = 0.5f * v * (1.f + tanhf(0.7978845608028654f * u));
          ((f16*)Cout)[off] = (f16)g;
        } else if constexpr (MODE == 1) {
          ((f16*)Cout)[off] = (f16)v;
        } else {
          ((float*)Cout)[off] = v;
        }
      }
    }
  }
}

// ---------- fused conv + block-diag dual gate GEMM + RG-LRU + chunk summaries ----------
// MERGED-HEAD version: one block = 128 m-rows (one scan chunk) x ONE FULL HEAD (256 cols),
// 512 threads / 8 waves (2m x 4n, 64x64 dual output per wave). The conv tile is computed
// ONCE per (chunk, head) instead of twice (the old half-blocks duplicated it).
// LDS: As [128x256] f16 conv tile (64 KB, XOR-swizzled granules) + Bi/Ba [256x32] (16 KB each).
__global__ __launch_bounds__(512, 2) void gates_fused(
    const f16* __restrict__ XBh, const float* __restrict__ cw, const float* __restrict__ cb,
    const f16* __restrict__ BiT, const f16* __restrict__ BaT,
    const float* __restrict__ ib, const float* __restrict__ ab,
    const float* __restrict__ spT, const int* __restrict__ segpos,
    uint32_t* __restrict__ AN, float* __restrict__ Ac, float* __restrict__ Hc) {
  __shared__ __align__(16) f16 As[128 * 256];   // 64 KB
  __shared__ __align__(16) f16 Bi[256 * 32];    // 16 KB (reused as carry after k-loop)
  __shared__ __align__(16) f16 Ba[256 * 32];    // 16 KB -> 96 KB total, 1 block/CU (8 waves)
  const int m0 = blockIdx.x * 128;
  const int h = blockIdx.y;
  const int ncol0 = h * HDIM;
  const int t = threadIdx.x;
  const int lane = t & 63, wave = t >> 6;
  const int wr = (wave >> 2) * 64;       // m-half: {0,64}
  const int wc = (wave & 3) * 64;        // n-quarter within head: {0,64,128,192}
  const int l15 = lane & 15, quad = lane >> 4;

  // ---- pre-issue k0=0 B stages: they land under the conv prologue ----
  const int srow = t >> 2, scol = (t & 3) * 8;
  const f16* Big = BiT + (long long)(ncol0 + srow) * HDIM + scol;
  const f16* Bag = BaT + (long long)(ncol0 + srow) * HDIM + scol;
  gl2lds16(Big, &Bi[t * 8]);
  gl2lds16(Big + (long long)128 * HDIM, &Bi[128 * 32 + t * 8]);
  gl2lds16(Bag, &Ba[t * 8]);
  gl2lds16(Bag + (long long)128 * HDIM, &Ba[128 * 32 + t * 8]);

  // ---- conv prologue: As[r][k] = conv(m0+r, ncol0+k), swizzled granules, ONCE ----
#pragma unroll 4
  for (int it = 0; it < 8; ++it) {
    int idx = it * 512 + t;
    int r = idx >> 5, kc = idx & 31;          // granule kc = 8 f16 = 16 B
    int m = m0 + r, tpos = m & (TSEQ - 1);
    int colbase = ncol0 + kc * 8;
    float acc[8];
    {
      float4 c0 = *(const float4*)&cb[colbase];
      float4 c1 = *(const float4*)&cb[colbase + 4];
      acc[0] = c0.x; acc[1] = c0.y; acc[2] = c0.z; acc[3] = c0.w;
      acc[4] = c1.x; acc[5] = c1.y; acc[6] = c1.z; acc[7] = c1.w;
    }
#pragma unroll
    for (int d = 0; d < 4; ++d) {
      if (tpos >= d) {
        f16x8 xv = *(const f16x8*)&XBh[(long long)(m - d) * LRU + colbase];
        float4 w0 = *(const float4*)&cw[(3 - d) * LRU + colbase];
        float4 w1 = *(const float4*)&cw[(3 - d) * LRU + colbase + 4];
        acc[0] += w0.x * (float)xv[0]; acc[1] += w0.y * (float)xv[1];
        acc[2] += w0.z * (float)xv[2]; acc[3] += w0.w * (float)xv[3];
        acc[4] += w1.x * (float)xv[4]; acc[5] += w1.y * (float)xv[5];
        acc[6] += w1.z * (float)xv[6]; acc[7] += w1.w * (float)xv[7];
      }
    }
    f16x8 o;
#pragma unroll
    for (int k = 0; k < 8; ++k) o[k] = (f16)acc[k];
    int gs = (kc & ~7) | ((kc ^ r) & 7);      // XOR bank-group swizzle
    *(f16x8*)&As[r * 256 + gs * 8] = o;
  }
  __syncthreads();   // conv visible + k0=0 B-tiles landed (syncthreads drains vmcnt)

  // ---- dual GEMM k-loop over the head's 256 k-cols (single-buffered B) ----
  f32x4 ci[4][4] = {};
  f32x4 ca[4][4] = {};
  for (int k0 = 0; k0 < HDIM; k0 += 32) {
    f16x8 af[4], bif[4], baf[4];
#pragma unroll
    for (int i = 0; i < 4; ++i) {
      int row = wr + i * 16 + l15;
      int g = (k0 >> 3) + quad;
      int gsw = (g & ~7) | ((g ^ row) & 7);
      af[i] = *(const f16x8*)&As[row * 256 + gsw * 8];
    }
#pragma unroll
    for (int j = 0; j < 4; ++j) {
      bif[j] = *(const f16x8*)&Bi[(wc + j * 16 + l15) * 32 + quad * 8];
      baf[j] = *(const f16x8*)&Ba[(wc + j * 16 + l15) * 32 + quad * 8];
    }
#pragma unroll
    for (int i = 0; i < 4; ++i)
#pragma unroll
      for (int j = 0; j < 4; ++j) {
        ci[i][j] = __builtin_amdgcn_mfma_f32_16x16x32_f16(af[i], bif[j], ci[i][j], 0, 0, 0);
        ca[i][j] = __builtin_amdgcn_mfma_f32_16x16x32_f16(af[i], baf[j], ca[i][j], 0, 0, 0);
      }
    __syncthreads();   // all reads of Bi/Ba done (WAR for restage)
    if (k0 + 32 < HDIM) {
      const f16* bi2 = Big + (k0 + 32);
      const f16* ba2 = Bag + (k0 + 32);
      gl2lds16(bi2, &Bi[t * 8]);
      gl2lds16(bi2 + (long long)128 * HDIM, &Bi[128 * 32 + t * 8]);
      gl2lds16(ba2, &Ba[t * 8]);
      gl2lds16(ba2 + (long long)128 * HDIM, &Ba[128 * 32 + t * 8]);
      __syncthreads(); // staged tiles landed + visible
    }
  }

  // ---- epilogue: RG-LRU elementwise, pack AN, and per-column chunk summaries ----
  const int mb = m0 >> 12;                 // batch index (4096 rows/batch)
  const int cch = (m0 & (TSEQ - 1)) >> 7;  // chunk within batch
  // hoisted segment-start flags for this thread's 16 rows (4x int4 loads)
  uint32_t rsmask = 0;
#pragma unroll
  for (int i = 0; i < 4; ++i) {
    int4 sp4 = *(const int4*)&segpos[m0 + wr + i * 16 + quad * 4];
    rsmask |= (sp4.x == 0 ? 1u : 0u) << (i * 4 + 0);
    rsmask |= (sp4.y == 0 ? 1u : 0u) << (i * 4 + 1);
    rsmask |= (sp4.z == 0 ? 1u : 0u) << (i * 4 + 2);
    rsmask |= (sp4.w == 0 ? 1u : 0u) << (i * 4 + 3);
  }
  float Aw[4], hw[4];                      // per-j wave-level (64-row) summaries
#pragma unroll
  for (int j = 0; j < 4; ++j) {
    const int cl = wc + j * 16 + l15;      // head-local col 0..255
    const int col = ncol0 + cl;
    const float ibv = ib[col], abv = ab[col];
    const float sp = spT[col];
    float A4[4], h4[4];
#pragma unroll
    for (int i = 0; i < 4; ++i) {
      float Aseg = 1.f, hseg = 0.f;
#pragma unroll
      for (int r = 0; r < 4; ++r) {
        const int rowL = wr + i * 16 + quad * 4 + r;
        const int row = m0 + rowL;
        float gx = fast_sigmoid(ci[i][j][r] + ibv);
        float ga = fast_sigmoid(ca[i][j][r] + abv);
        float la = -8.f * ga * sp;
        bool rs = (rsmask >> (i * 4 + r)) & 1u;
        float a = rs ? 0.f : __expf(la);
        uint32_t afx = __float2uint_rn(a * 65536.f);
        if (afx > 65535u) afx = 65535u;
        float aq = (float)afx * (1.f / 65536.f);
        // conv value from swizzled LDS
        int g = cl >> 3, e = cl & 7;
        int gsw = (g & ~7) | ((g ^ rowL) & 7);
        float cv = (float)As[rowL * 256 + gsw * 8 + e];
        float mult = rs ? 1.f : sqrtf(fmaxf(1.f - aq * aq, 0.f));
        f16 nh = (f16)(cv * gx * mult);
        AN[(long long)row * LRU + col] =
            afx | ((uint32_t)__builtin_bit_cast(uint16_t, nh) << 16);
        float xq = (float)nh;
        hseg = aq * hseg + xq;   // scan over r (rows ascending)
        Aseg *= aq;
      }
      A4[i] = Aseg; h4[i] = hseg;
    }
    // cross-quad composition (rows quad*4.. ascending), Kogge-Stone over stride-16 lanes
#pragma unroll
    for (int i = 0; i < 4; ++i) {
      float A = A4[i], hv = h4[i];
#pragma unroll
      for (int d = 1; d <= 2; d <<= 1) {
        int src = quad >= d ? lane - 16 * d : lane;
        float Ap = __shfl(A, src);
        float hp = __shfl(hv, src);
        if (quad >= d) { hv = A * hp + hv; A = Ap * A; }
      }
      A4[i] = __shfl(A, 48 + l15);   // 16-row block total (from quad 3)
      h4[i] = __shfl(hv, 48 + l15);
    }
    float Awv = 1.f, hwv = 0.f;
#pragma unroll
    for (int i = 0; i < 4; ++i) { hwv = A4[i] * hwv + h4[i]; Awv *= A4[i]; }
    Aw[j] = Awv; hw[j] = hwv;
  }
  // cross-wave composition via LDS (reuse Bi space; k-loop is done)
  float* carry = (float*)Bi;   // [256 cols][2]
  __syncthreads();
  if (wr == 0 && quad == 0) {
#pragma unroll
    for (int j = 0; j < 4; ++j) {
      int cl = wc + j * 16 + l15;
      carry[cl * 2] = Aw[j]; carry[cl * 2 + 1] = hw[j];
    }
  }
  __syncthreads();
  if (wr == 64 && quad == 0) {
#pragma unroll
    for (int j = 0; j < 4; ++j) {
      int cl = wc + j * 16 + l15;
      float At = carry[cl * 2], ht = carry[cl * 2 + 1];
      float A = At * Aw[j];
      float hv = Aw[j] * ht + hw[j];
      int o = (mb * NC + cch) * LRU + ncol0 + cl;
      Ac[o] = A; Hc[o] = hv;
    }
  }
}

// ---------- merged scan pass 2+3: recompute chunk prefix, apply, emit G ----------
__global__ void scan23_kernel(const uint32_t* __restrict__ AN,
                              const float* __restrict__ Ac, const float* __restrict__ Hc,
                              const f16* __restrict__ Yh, f16* __restrict__ G) {
  int l = blockIdx.x * 256 + threadIdx.x;
  int c = blockIdx.y, b = blockIdx.z;
  // chunk-prefix over chunks < c (Ac/Hc are tiny, L2-resident)
  float hv = 0.f;
  for (int cc = 0; cc < c; ++cc) {
    int o = (b * NC + cc) * LRU + l;
    hv = Ac[o] * hv + Hc[o];
  }
  long long base = ((long long)b * TSEQ + (long long)c * CT) * LRU + l;
#pragma unroll 4
  for (int s = 0; s < CT; ++s) {
    long long o = base + (long long)s * LRU;
    uint32_t p = AN[o];
    float a = (float)(p & 0xFFFFu) * (1.f / 65536.f);
    float x = f16bits_to_f(p >> 16);
    hv = a * hv + x;
    G[o] = (f16)(hv * (float)Yh[o]);
  }
}

extern "C" void kernel_launch(void* const* d_in, const int* in_sizes, int n_in,
                              void* d_out, int out_size, void* d_ws, size_t ws_size,
                              hipStream_t stream) {
  (void)in_sizes; (void)n_in; (void)out_size; (void)ws_size;
  const float* x          = (const float*)d_in[0];
  const int*   segment_pos= (const int*)d_in[1];
  const float* w_y        = (const float*)d_in[2];
  const float* b_y        = (const float*)d_in[3];
  const float* w_x        = (const float*)d_in[4];
  const float* b_x        = (const float*)d_in[5];
  const float* w_out      = (const float*)d_in[6];
  const float* b_out      = (const float*)d_in[7];
  const float* conv_w     = (const float*)d_in[8];
  const float* conv_b     = (const float*)d_in[9];
  const float* a_param    = (const float*)d_in[10];
  const float* igate_w    = (const float*)d_in[11];
  const float* igate_b    = (const float*)d_in[12];
  const float* agate_w    = (const float*)d_in[13];
  const float* agate_b    = (const float*)d_in[14];
  float* out = (float*)d_out;

  char* base = (char*)d_ws;
  size_t off = 0;
  auto alloc = [&](size_t nbytes) -> void* {
    void* p = base + off;
    off = (off + nbytes + 255) & ~(size_t)255;
    return p;
  };
  f16*     Xh    = (f16*)alloc((size_t)MTOT * LRU * 2);
  f16*     Yh    = (f16*)alloc((size_t)MTOT * LRU * 2);
  f16*     XBh   = (f16*)alloc((size_t)MTOT * LRU * 2);
  uint32_t* AN   = (uint32_t*)alloc((size_t)MTOT * LRU * 4);
  f16*     wyT   = (f16*)alloc((size_t)WID * LRU * 2);
  f16*     wxT   = (f16*)alloc((size_t)WID * LRU * 2);
  f16*     woutT = (f16*)alloc((size_t)LRU * WID * 2);
  f16*     igwT  = (f16*)alloc((size_t)NHEAD * HDIM * HDIM * 2);
  f16*     agwT  = (f16*)alloc((size_t)NHEAD * HDIM * HDIM * 2);
  float*   Ac    = (float*)alloc((size_t)BATCH * NC * LRU * 4);
  float*   Hc    = (float*)alloc((size_t)BATCH * NC * LRU * 4);
  float*   spT   = (float*)alloc((size_t)LRU * 4);
  f16*     G     = Xh;   // Xh dead after the input GEMMs

  // prep: cast + all weight transposes + softplus table in one launch
  prep_kernel<<<29704, 256, 0, stream>>>(x, Xh, w_y, w_x, w_out, wyT, wxT, woutT,
                                         igate_w, agate_w, igwT, agwT, a_param, spT);
  // input GEMMs: linear_y + gelu, then linear_x (A=Xh re-read is L3-resident)
  gemm_128<0><<<dim3(MTOT / 128, LRU / 128), 256, 0, stream>>>(
      Xh, wyT, b_y, Yh, MTOT, LRU, WID);
  gemm_128<1><<<dim3(MTOT / 128, LRU / 128), 256, 0, stream>>>(
      Xh, wxT, b_x, XBh, MTOT, LRU, WID);
  // fused conv + gates + RG-LRU + chunk summaries (one block per chunk x head)
  gates_fused<<<dim3(MTOT / 128, NHEAD), 512, 0, stream>>>(
      XBh, conv_w, conv_b, igwT, agwT, igate_b, agate_b, spT, segment_pos, AN, Ac, Hc);
  // merged chunk-prefix + final scan + G emission
  scan23_kernel<<<dim3(LRU / 256, NC, BATCH), 256, 0, stream>>>(AN, Ac, Hc, Yh, G);
  // output projection
  gemm_128<2><<<dim3(MTOT / 128, WID / 128), 256, 0, stream>>>(
      G, woutT, b_out, out, MTOT, WID, LRU);
}

// Round 9
// 480.825 us; speedup vs baseline: 1.0429x; 1.0429x over previous
//
#include <hip/hip_runtime.h>
#include <cstdint>
#include <math.h>

typedef _Float16 f16;
typedef f16 f16x8 __attribute__((ext_vector_type(8)));
typedef f16 f16x4 __attribute__((ext_vector_type(4)));
typedef float f32x4 __attribute__((ext_vector_type(4)));

#define BATCH 2
#define TSEQ 4096
#define WID 2048
#define LRU 2048
#define NHEAD 8
#define HDIM 256
#define MTOT (BATCH * TSEQ)   // 8192
#define CT 128                // scan chunk length == gates m-tile
#define NC (TSEQ / CT)        // 32 chunks

// ---------- async global -> LDS, 16B per lane ----------
__device__ __forceinline__ void gl2lds16(const f16* g, f16* l) {
  __builtin_amdgcn_global_load_lds(
      (__attribute__((address_space(1))) uint32_t*)(uintptr_t)g,
      (__attribute__((address_space(3))) uint32_t*)(uint32_t)(uintptr_t)l,
      16, 0, 0);
}

__device__ __forceinline__ float fast_rcp(float x) {
  float r; asm("v_rcp_f32 %0, %1" : "=v"(r) : "v"(x)); return r;
}
// fast sigmoid: v_exp-based exp (2 inst) + v_rcp (1 inst). ~1 ulp vs libm;
// downstream values are f16/16-bit-fixed quantized, so this is below the
// existing quantization noise floor.
__device__ __forceinline__ float fast_sigmoid(float x) {
  return fast_rcp(1.f + __expf(-x));
}
__device__ __forceinline__ float f16bits_to_f(uint32_t b) {
  return (float)__builtin_bit_cast(f16, (uint16_t)b);
}

// ---------- prep megakernel: cast x -> f16, transpose+cast all weights, softplus table ----------
// blocks [0,16384): cast; [16384,28672): 3x 2048^2 transpose; [28672,29696): 16x 256^2;
// [29696,29704): spT = softplus(a_param) (precise libm, computed once)
__global__ void prep_kernel(const float* __restrict__ x, f16* __restrict__ Xh,
                            const float* __restrict__ w_y, const float* __restrict__ w_x,
                            const float* __restrict__ w_out,
                            f16* __restrict__ wyT, f16* __restrict__ wxT, f16* __restrict__ woutT,
                            const float* __restrict__ ig, const float* __restrict__ ag,
                            f16* __restrict__ igT, f16* __restrict__ agT,
                            const float* __restrict__ ap, float* __restrict__ spT) {
  __shared__ float tile[32][33];
  const int bid = blockIdx.x, t = threadIdx.x;
  if (bid < 16384) {
    int i = bid * 256 + t;
    float4 v = ((const float4*)x)[i];
    f16x4 o = { (f16)v.x, (f16)v.y, (f16)v.z, (f16)v.w };
    ((f16x4*)Xh)[i] = o;
    return;
  }
  if (bid >= 29696) {
    int i = (bid - 29696) * 256 + t;
    spT[i] = log1pf(expf(ap[i]));
    return;
  }
  const int tx = t & 31, ty = t >> 5;
  const float* ib; f16* ob; int R, C, c0, r0;
  if (bid < 28672) {
    int idx = bid - 16384;
    int z = idx >> 12, tl = idx & 4095;
    ib = z == 0 ? w_y : (z == 1 ? w_x : w_out);
    ob = z == 0 ? wyT : (z == 1 ? wxT : woutT);
    R = 2048; C = 2048;
    c0 = (tl & 63) * 32; r0 = (tl >> 6) * 32;
  } else {
    int idx = bid - 28672;
    int z = idx >> 6, tl = idx & 63;
    ib = (z < 8 ? ig : ag) + (long long)(z & 7) * HDIM * HDIM;
    ob = (z < 8 ? igT : agT) + (long long)(z & 7) * HDIM * HDIM;
    R = HDIM; C = HDIM;
    c0 = (tl & 7) * 32; r0 = (tl >> 3) * 32;
  }
#pragma unroll
  for (int i = 0; i < 32; i += 8)
    tile[ty + i][tx] = ib[(long long)(r0 + ty + i) * C + c0 + tx];
  __syncthreads();
#pragma unroll
  for (int i = 0; i < 32; i += 8)
    ob[(long long)(c0 + ty + i) * R + r0 + tx] = (f16)tile[tx][ty + i];
}

// ---------- 128x128 m97-style GEMM, BK=64, 4 blocks/CU ----------
// C[M,N] = A[M,K] @ BT[N,K]^T + bias.  MODE 0: f16 out, fast-GELU; 1: f16 out; 2: f32 out.
// Occupancy does the latency hiding (m97 mechanism): single-buffered 32 KB LDS,
// plain __syncthreads (full drain), 4 blocks x 4 waves = 16 waves/CU; cross-block
// wave overlap fills the matrix pipe during this block's stage/drain/read regions.
// Unified reg usage is exactly 128 (64 VGPR + 64 acc, from R8 CSV) = 512/4, so 4
// waves/SIMD fits without spill; LDS 4 x 32 KB = 128 KB <= 160 KB.
// 16B-granule XOR swizzle (involution g ^= row&7) applied to BOTH the global source
// column and the LDS read slot; LDS dest stays linear (global_load_lds-safe; 0-conflict
// verified by SQ_LDS_BANK_CONFLICT=0 with the same pattern).
template <int MODE>
__global__ __launch_bounds__(256, 4) void gemm_128(
    const f16* __restrict__ A, const f16* __restrict__ BT,
    const float* __restrict__ bias, void* __restrict__ Cout,
    int M, int N, int K) {
  __shared__ __align__(16) f16 As[128 * 64];   // 16 KB
  __shared__ __align__(16) f16 Bs[128 * 64];   // 16 KB
  const int m0 = blockIdx.x * 128, n0 = blockIdx.y * 128;
  const int t = threadIdx.x;
  const int lane = t & 63, wave = t >> 6;
  const int wr = (wave >> 1) * 64, wc = (wave & 1) * 64;
  const int l15 = lane & 15, quad = lane >> 4;
  const int srow = t >> 3;                       // 0..31 (8 threads x 16B per 128B row)
  const int sg = ((t & 7) ^ (srow & 7)) * 8;     // swizzled source granule col (f16 units)

  const f16* Ag = A + (long long)(m0 + srow) * K + sg;
  const f16* Bg = BT + (long long)(n0 + srow) * K + sg;
  const long long r32 = (long long)32 * K;       // +32 rows: row&7 invariant

  f32x4 c[4][4] = {};
  const int NT = K >> 6;
  for (int kt = 0; kt < NT; ++kt) {
    const f16* a = Ag + kt * 64;
    const f16* b = Bg + kt * 64;
#pragma unroll
    for (int cc = 0; cc < 4; ++cc) {
      gl2lds16(a + cc * r32, &As[cc * 2048 + t * 8]);
      gl2lds16(b + cc * r32, &Bs[cc * 2048 + t * 8]);
    }
    __syncthreads();   // drains vmcnt: tiles landed + visible
    f16x8 af[4][2], bf[4][2];
#pragma unroll
    for (int f = 0; f < 4; ++f) {
#pragma unroll
      for (int kh = 0; kh < 2; ++kh) {
        const int sa = ((kh * 4 + quad) ^ (l15 & 7)) * 8;   // swizzled read slot
        af[f][kh] = *(const f16x8*)&As[(wr + f * 16 + l15) * 64 + sa];
        bf[f][kh] = *(const f16x8*)&Bs[(wc + f * 16 + l15) * 64 + sa];
      }
    }
#pragma unroll
    for (int kh = 0; kh < 2; ++kh)
#pragma unroll
      for (int i = 0; i < 4; ++i)
#pragma unroll
        for (int j = 0; j < 4; ++j)
          c[i][j] = __builtin_amdgcn_mfma_f32_16x16x32_f16(af[i][kh], bf[j][kh], c[i][j], 0, 0, 0);
    __syncthreads();   // all reads done before next stage overwrites (WAR)
  }
#pragma unroll
  for (int i = 0; i < 4; ++i) {
#pragma unroll
    for (int j = 0; j < 4; ++j) {
      const int col = n0 + wc + j * 16 + l15;
      const float bv = bias[col];
      const int row0 = m0 + wr + i * 16 + quad * 4;
#pragma unroll
      for (int r = 0; r < 4; ++r) {
        float v = c[i][j][r] + bv;
        long long off = (long long)(row0 + r) * N + col;
        if constexpr (MODE == 0) {
          // gelu_tanh(v) = v * sigmoid(2z), z = 0.79788456(v + 0.044715 v^3)
          float z2 = 1.5957691216057308f * (v + 0.044715f * v * v * v);
          ((f16*)Cout)[off] = (f16)(v * fast_sigmoid(z2));
        } else if constexpr (MODE == 1) {
          ((f16*)Cout)[off] = (f16)v;
        } else {
          ((float*)Cout)[off] = v;
        }
      }
    }
  }
}

// ---------- fused conv + block-diag dual gate GEMM + RG-LRU + chunk summaries ----------
// MERGED-HEAD version: one block = 128 m-rows (one scan chunk) x ONE FULL HEAD (256 cols),
// 512 threads / 8 waves (2m x 4n, 64x64 dual output per wave). The conv tile is computed
// ONCE per (chunk, head) instead of twice (the old half-blocks duplicated it).
// LDS: As [128x256] f16 conv tile (64 KB, XOR-swizzled granules) + Bi/Ba [256x32] (16 KB each).
__global__ __launch_bounds__(512, 2) void gates_fused(
    const f16* __restrict__ XBh, const float* __restrict__ cw, const float* __restrict__ cb,
    const f16* __restrict__ BiT, const f16* __restrict__ BaT,
    const float* __restrict__ ib, const float* __restrict__ ab,
    const float* __restrict__ spT, const int* __restrict__ segpos,
    uint32_t* __restrict__ AN, float* __restrict__ Ac, float* __restrict__ Hc) {
  __shared__ __align__(16) f16 As[128 * 256];   // 64 KB
  __shared__ __align__(16) f16 Bi[256 * 32];    // 16 KB (reused as carry after k-loop)
  __shared__ __align__(16) f16 Ba[256 * 32];    // 16 KB -> 96 KB total, 1 block/CU (8 waves)
  const int m0 = blockIdx.x * 128;
  const int h = blockIdx.y;
  const int ncol0 = h * HDIM;
  const int t = threadIdx.x;
  const int lane = t & 63, wave = t >> 6;
  const int wr = (wave >> 2) * 64;       // m-half: {0,64}
  const int wc = (wave & 3) * 64;        // n-quarter within head: {0,64,128,192}
  const int l15 = lane & 15, quad = lane >> 4;

  // ---- pre-issue k0=0 B stages: they land under the conv prologue ----
  const int srow = t >> 2, scol = (t & 3) * 8;
  const f16* Big = BiT + (long long)(ncol0 + srow) * HDIM + scol;
  const f16* Bag = BaT + (long long)(ncol0 + srow) * HDIM + scol;
  gl2lds16(Big, &Bi[t * 8]);
  gl2lds16(Big + (long long)128 * HDIM, &Bi[128 * 32 + t * 8]);
  gl2lds16(Bag, &Ba[t * 8]);
  gl2lds16(Bag + (long long)128 * HDIM, &Ba[128 * 32 + t * 8]);

  // ---- conv prologue: As[r][k] = conv(m0+r, ncol0+k), swizzled granules, ONCE ----
#pragma unroll 4
  for (int it = 0; it < 8; ++it) {
    int idx = it * 512 + t;
    int r = idx >> 5, kc = idx & 31;          // granule kc = 8 f16 = 16 B
    int m = m0 + r, tpos = m & (TSEQ - 1);
    int colbase = ncol0 + kc * 8;
    float acc[8];
    {
      float4 c0 = *(const float4*)&cb[colbase];
      float4 c1 = *(const float4*)&cb[colbase + 4];
      acc[0] = c0.x; acc[1] = c0.y; acc[2] = c0.z; acc[3] = c0.w;
      acc[4] = c1.x; acc[5] = c1.y; acc[6] = c1.z; acc[7] = c1.w;
    }
#pragma unroll
    for (int d = 0; d < 4; ++d) {
      if (tpos >= d) {
        f16x8 xv = *(const f16x8*)&XBh[(long long)(m - d) * LRU + colbase];
        float4 w0 = *(const float4*)&cw[(3 - d) * LRU + colbase];
        float4 w1 = *(const float4*)&cw[(3 - d) * LRU + colbase + 4];
        acc[0] += w0.x * (float)xv[0]; acc[1] += w0.y * (float)xv[1];
        acc[2] += w0.z * (float)xv[2]; acc[3] += w0.w * (float)xv[3];
        acc[4] += w1.x * (float)xv[4]; acc[5] += w1.y * (float)xv[5];
        acc[6] += w1.z * (float)xv[6]; acc[7] += w1.w * (float)xv[7];
      }
    }
    f16x8 o;
#pragma unroll
    for (int k = 0; k < 8; ++k) o[k] = (f16)acc[k];
    int gs = (kc & ~7) | ((kc ^ r) & 7);      // XOR bank-group swizzle
    *(f16x8*)&As[r * 256 + gs * 8] = o;
  }
  __syncthreads();   // conv visible + k0=0 B-tiles landed (syncthreads drains vmcnt)

  // ---- dual GEMM k-loop over the head's 256 k-cols (single-buffered B) ----
  f32x4 ci[4][4] = {};
  f32x4 ca[4][4] = {};
  for (int k0 = 0; k0 < HDIM; k0 += 32) {
    f16x8 af[4], bif[4], baf[4];
#pragma unroll
    for (int i = 0; i < 4; ++i) {
      int row = wr + i * 16 + l15;
      int g = (k0 >> 3) + quad;
      int gsw = (g & ~7) | ((g ^ row) & 7);
      af[i] = *(const f16x8*)&As[row * 256 + gsw * 8];
    }
#pragma unroll
    for (int j = 0; j < 4; ++j) {
      bif[j] = *(const f16x8*)&Bi[(wc + j * 16 + l15) * 32 + quad * 8];
      baf[j] = *(const f16x8*)&Ba[(wc + j * 16 + l15) * 32 + quad * 8];
    }
#pragma unroll
    for (int i = 0; i < 4; ++i)
#pragma unroll
      for (int j = 0; j < 4; ++j) {
        ci[i][j] = __builtin_amdgcn_mfma_f32_16x16x32_f16(af[i], bif[j], ci[i][j], 0, 0, 0);
        ca[i][j] = __builtin_amdgcn_mfma_f32_16x16x32_f16(af[i], baf[j], ca[i][j], 0, 0, 0);
      }
    __syncthreads();   // all reads of Bi/Ba done (WAR for restage)
    if (k0 + 32 < HDIM) {
      const f16* bi2 = Big + (k0 + 32);
      const f16* ba2 = Bag + (k0 + 32);
      gl2lds16(bi2, &Bi[t * 8]);
      gl2lds16(bi2 + (long long)128 * HDIM, &Bi[128 * 32 + t * 8]);
      gl2lds16(ba2, &Ba[t * 8]);
      gl2lds16(ba2 + (long long)128 * HDIM, &Ba[128 * 32 + t * 8]);
      __syncthreads(); // staged tiles landed + visible
    }
  }

  // ---- epilogue: RG-LRU elementwise, pack AN, and per-column chunk summaries ----
  const int mb = m0 >> 12;                 // batch index (4096 rows/batch)
  const int cch = (m0 & (TSEQ - 1)) >> 7;  // chunk within batch
  // hoisted segment-start flags for this thread's 16 rows (4x int4 loads)
  uint32_t rsmask = 0;
#pragma unroll
  for (int i = 0; i < 4; ++i) {
    int4 sp4 = *(const int4*)&segpos[m0 + wr + i * 16 + quad * 4];
    rsmask |= (sp4.x == 0 ? 1u : 0u) << (i * 4 + 0);
    rsmask |= (sp4.y == 0 ? 1u : 0u) << (i * 4 + 1);
    rsmask |= (sp4.z == 0 ? 1u : 0u) << (i * 4 + 2);
    rsmask |= (sp4.w == 0 ? 1u : 0u) << (i * 4 + 3);
  }
  float Aw[4], hw[4];                      // per-j wave-level (64-row) summaries
#pragma unroll
  for (int j = 0; j < 4; ++j) {
    const int cl = wc + j * 16 + l15;      // head-local col 0..255
    const int col = ncol0 + cl;
    const float ibv = ib[col], abv = ab[col];
    const float sp = spT[col];
    float A4[4], h4[4];
#pragma unroll
    for (int i = 0; i < 4; ++i) {
      float Aseg = 1.f, hseg = 0.f;
#pragma unroll
      for (int r = 0; r < 4; ++r) {
        const int rowL = wr + i * 16 + quad * 4 + r;
        const int row = m0 + rowL;
        float gx = fast_sigmoid(ci[i][j][r] + ibv);
        float ga = fast_sigmoid(ca[i][j][r] + abv);
        float la = -8.f * ga * sp;
        bool rs = (rsmask >> (i * 4 + r)) & 1u;
        float a = rs ? 0.f : __expf(la);
        uint32_t afx = __float2uint_rn(a * 65536.f);
        if (afx > 65535u) afx = 65535u;
        float aq = (float)afx * (1.f / 65536.f);
        // conv value from swizzled LDS
        int g = cl >> 3, e = cl & 7;
        int gsw = (g & ~7) | ((g ^ rowL) & 7);
        float cv = (float)As[rowL * 256 + gsw * 8 + e];
        float mult = rs ? 1.f : sqrtf(fmaxf(1.f - aq * aq, 0.f));
        f16 nh = (f16)(cv * gx * mult);
        AN[(long long)row * LRU + col] =
            afx | ((uint32_t)__builtin_bit_cast(uint16_t, nh) << 16);
        float xq = (float)nh;
        hseg = aq * hseg + xq;   // scan over r (rows ascending)
        Aseg *= aq;
      }
      A4[i] = Aseg; h4[i] = hseg;
    }
    // cross-quad composition (rows quad*4.. ascending), Kogge-Stone over stride-16 lanes
#pragma unroll
    for (int i = 0; i < 4; ++i) {
      float A = A4[i], hv = h4[i];
#pragma unroll
      for (int d = 1; d <= 2; d <<= 1) {
        int src = quad >= d ? lane - 16 * d : lane;
        float Ap = __shfl(A, src);
        float hp = __shfl(hv, src);
        if (quad >= d) { hv = A * hp + hv; A = Ap * A; }
      }
      A4[i] = __shfl(A, 48 + l15);   // 16-row block total (from quad 3)
      h4[i] = __shfl(hv, 48 + l15);
    }
    float Awv = 1.f, hwv = 0.f;
#pragma unroll
    for (int i = 0; i < 4; ++i) { hwv = A4[i] * hwv + h4[i]; Awv *= A4[i]; }
    Aw[j] = Awv; hw[j] = hwv;
  }
  // cross-wave composition via LDS (reuse Bi space; k-loop is done)
  float* carry = (float*)Bi;   // [256 cols][2]
  __syncthreads();
  if (wr == 0 && quad == 0) {
#pragma unroll
    for (int j = 0; j < 4; ++j) {
      int cl = wc + j * 16 + l15;
      carry[cl * 2] = Aw[j]; carry[cl * 2 + 1] = hw[j];
    }
  }
  __syncthreads();
  if (wr == 64 && quad == 0) {
#pragma unroll
    for (int j = 0; j < 4; ++j) {
      int cl = wc + j * 16 + l15;
      float At = carry[cl * 2], ht = carry[cl * 2 + 1];
      float A = At * Aw[j];
      float hv = Aw[j] * ht + hw[j];
      int o = (mb * NC + cch) * LRU + ncol0 + cl;
      Ac[o] = A; Hc[o] = hv;
    }
  }
}

// ---------- merged scan pass 2+3: recompute chunk prefix, apply, emit G ----------
// 2 columns per thread: uint2 AN loads (8 B/lane), packed Yh/G words, two
// independent scan chains per thread (ILP in the dependent-FMA latency).
__global__ void scan23_kernel(const uint32_t* __restrict__ AN,
                              const float* __restrict__ Ac, const float* __restrict__ Hc,
                              const f16* __restrict__ Yh, f16* __restrict__ G) {
  const int l = (blockIdx.x * 256 + threadIdx.x) * 2;
  const int c = blockIdx.y, b = blockIdx.z;
  // chunk-prefix over chunks < c (Ac/Hc are tiny, L2-resident)
  float h0 = 0.f, h1 = 0.f;
  for (int cc = 0; cc < c; ++cc) {
    const int o = (b * NC + cc) * LRU + l;
    const float2 A2 = *(const float2*)&Ac[o];
    const float2 H2 = *(const float2*)&Hc[o];
    h0 = A2.x * h0 + H2.x;
    h1 = A2.y * h1 + H2.y;
  }
  long long base = ((long long)b * TSEQ + (long long)c * CT) * LRU + l;
#pragma unroll 8
  for (int s = 0; s < CT; ++s) {
    const long long o = base + (long long)s * LRU;
    const uint2 p = *(const uint2*)&AN[o];
    const uint32_t yb = *(const uint32_t*)&Yh[o];
    const float a0 = (float)(p.x & 0xFFFFu) * (1.f / 65536.f);
    const float x0 = f16bits_to_f(p.x >> 16);
    const float a1 = (float)(p.y & 0xFFFFu) * (1.f / 65536.f);
    const float x1 = f16bits_to_f(p.y >> 16);
    h0 = a0 * h0 + x0;
    h1 = a1 * h1 + x1;
    const f16 g0 = (f16)(h0 * f16bits_to_f(yb & 0xFFFFu));
    const f16 g1 = (f16)(h1 * f16bits_to_f(yb >> 16));
    *(uint32_t*)&G[o] = ((uint32_t)__builtin_bit_cast(uint16_t, g1) << 16)
                        | (uint32_t)__builtin_bit_cast(uint16_t, g0);
  }
}

extern "C" void kernel_launch(void* const* d_in, const int* in_sizes, int n_in,
                              void* d_out, int out_size, void* d_ws, size_t ws_size,
                              hipStream_t stream) {
  (void)in_sizes; (void)n_in; (void)out_size; (void)ws_size;
  const float* x          = (const float*)d_in[0];
  const int*   segment_pos= (const int*)d_in[1];
  const float* w_y        = (const float*)d_in[2];
  const float* b_y        = (const float*)d_in[3];
  const float* w_x        = (const float*)d_in[4];
  const float* b_x        = (const float*)d_in[5];
  const float* w_out      = (const float*)d_in[6];
  const float* b_out      = (const float*)d_in[7];
  const float* conv_w     = (const float*)d_in[8];
  const float* conv_b     = (const float*)d_in[9];
  const float* a_param    = (const float*)d_in[10];
  const float* igate_w    = (const float*)d_in[11];
  const float* igate_b    = (const float*)d_in[12];
  const float* agate_w    = (const float*)d_in[13];
  const float* agate_b    = (const float*)d_in[14];
  float* out = (float*)d_out;

  char* base = (char*)d_ws;
  size_t off = 0;
  auto alloc = [&](size_t nbytes) -> void* {
    void* p = base + off;
    off = (off + nbytes + 255) & ~(size_t)255;
    return p;
  };
  f16*     Xh    = (f16*)alloc((size_t)MTOT * LRU * 2);
  f16*     Yh    = (f16*)alloc((size_t)MTOT * LRU * 2);
  f16*     XBh   = (f16*)alloc((size_t)MTOT * LRU * 2);
  uint32_t* AN   = (uint32_t*)alloc((size_t)MTOT * LRU * 4);
  f16*     wyT   = (f16*)alloc((size_t)WID * LRU * 2);
  f16*     wxT   = (f16*)alloc((size_t)WID * LRU * 2);
  f16*     woutT = (f16*)alloc((size_t)LRU * WID * 2);
  f16*     igwT  = (f16*)alloc((size_t)NHEAD * HDIM * HDIM * 2);
  f16*     agwT  = (f16*)alloc((size_t)NHEAD * HDIM * HDIM * 2);
  float*   Ac    = (float*)alloc((size_t)BATCH * NC * LRU * 4);
  float*   Hc    = (float*)alloc((size_t)BATCH * NC * LRU * 4);
  float*   spT   = (float*)alloc((size_t)LRU * 4);
  f16*     G     = Xh;   // Xh dead after the input GEMMs

  // prep: cast + all weight transposes + softplus table in one launch
  prep_kernel<<<29704, 256, 0, stream>>>(x, Xh, w_y, w_x, w_out, wyT, wxT, woutT,
                                         igate_w, agate_w, igwT, agwT, a_param, spT);
  // input GEMMs: linear_y + gelu, then linear_x (A=Xh re-read is L3-resident)
  gemm_128<0><<<dim3(MTOT / 128, LRU / 128), 256, 0, stream>>>(
      Xh, wyT, b_y, Yh, MTOT, LRU, WID);
  gemm_128<1><<<dim3(MTOT / 128, LRU / 128), 256, 0, stream>>>(
      Xh, wxT, b_x, XBh, MTOT, LRU, WID);
  // fused conv + gates + RG-LRU + chunk summaries (one block per chunk x head)
  gates_fused<<<dim3(MTOT / 128, NHEAD), 512, 0, stream>>>(
      XBh, conv_w, conv_b, igwT, agwT, igate_b, agate_b, spT, segment_pos, AN, Ac, Hc);
  // merged chunk-prefix + final scan + G emission (2 cols/thread)
  scan23_kernel<<<dim3(LRU / 512, NC, BATCH), 256, 0, stream>>>(AN, Ac, Hc, Yh, G);
  // output projection
  gemm_128<2><<<dim3(MTOT / 128, WID / 128), 256, 0, stream>>>(
      G, woutT, b_out, out, MTOT, WID, LRU);
}